// Round 3
// baseline (231.275 us; speedup 1.0000x reference)
//
#include <hip/hip_runtime.h>

// RF grid-sample DAS beamforming.
// Shapes: d_tx[4,512,256] d_rx[128,512,256] apod[128,512,256] rf[4,128,3072] t0[4]
// out[4,512,256] fp32.
//
// R3 = R2 with the compile fix (half2_t must be __fp16-based to match
// __builtin_amdgcn_cvt_pkrtz's return type).
//
// R2 rationale: back to 4-angles-per-block (R1's angle split regressed: halved
// drx/apod amortization, doubled stage-barrier events). Changes vs R0 (93 us):
//  - rf staged in LDS as DUPLICATED fp16 pairs: lds[s] = {rf[s], rf[s+1]} as
//    packed half2 (4 B). One ds_read_b32 per interp instead of two b32 reads
//    -> LDS pipe cycles and bank conflicts (~40% of R0 runtime) both halve.
//    Precision: RTZ fp16 per-tap RMS err ~5e-4, random-walk over 128 elements
//    -> max output err ~0.015, well under the 0.0625 tolerance.
//  - T14 async-STAGE split: next element's rf loaded to registers during the
//    compute phase (issued after the staging barrier), converted+written next
//    iteration. Removes the all-wave stall on rf load latency.
//  - drx/apod loads hoisted into a 16-wide register batch before the interp
//    loop (R0's 64-VGPR compile had no headroom to cluster them).
// __launch_bounds__(512,4): 16 waves/CU (2 blocks), VGPR cap 128.
// Partial sums across 16 e-chunks via fp32 atomicAdd (out zeroed by memset).
// Data range: delay in [0,3070] => i0<=3070, i1<=3071: clamp is no-op safety;
// the duplicated pair at s=3071 (garbage second lane) is never read.

#define A_N 4
#define E_N 128
#define S_N 3072
#define NPIX_N (512 * 256)
#define TPB 512                    // threads per block (8 waves)
#define PXT 8                      // pixels per thread
#define TILE (TPB * PXT)           // 4096 pixels per block
#define TILES (NPIX_N / TILE)      // 32
#define ESPLIT 16                  // e-chunks
#define EPB (E_N / ESPLIT)         // 8 elements per block
#define SIT ((A_N * (S_N / 4)) / TPB)  // 3072 float4-slots / 512 thr = 6

typedef __fp16 half2_t __attribute__((ext_vector_type(2)));

__global__ __launch_bounds__(TPB, 4) void das_kernel(
    const float* __restrict__ d_tx, const float* __restrict__ d_rx,
    const float* __restrict__ apod, const float* __restrict__ rf,
    const float* __restrict__ t0,  float* __restrict__ out)
{
    __shared__ __align__(16) half2_t lds_rf[A_N * S_N];   // 48 KB
    const int tid = threadIdx.x;
    const int px0 = blockIdx.x * TILE + tid;   // + k*TPB for k in [0,PXT)
    const int e0  = blockIdx.y * EPB;

    float acc[A_N][PXT];
    float dta[A_N][PXT];
#pragma unroll
    for (int a = 0; a < A_N; ++a) {
        const float t0a = t0[a];
#pragma unroll
        for (int k = 0; k < PXT; ++k) {
            dta[a][k] = d_tx[a * NPIX_N + px0 + k * TPB] - t0a;
            acc[a][k] = 0.0f;
        }
    }

    // ---- rf prefetch registers (T14 issue-early / write-late) ----
    float4 pf[SIT];
    float  pe[SIT];   // rf[s+4]: first scalar of the next float4 (row-clamped)

    auto load_e = [&](int e) {
#pragma unroll
        for (int j = 0; j < SIT; ++j) {
            int idx = tid + j * TPB;          // float4 slot 0..3071
            int a   = idx / (S_N / 4);        // 0..3
            int s4  = idx - a * (S_N / 4);    // 0..767
            const float* r = rf + a * (E_N * S_N) + e * S_N + s4 * 4;
            pf[j] = *(const float4*)r;
            pe[j] = r[(s4 == (S_N / 4 - 1)) ? 3 : 4];  // clamped: pair at s=3071 never read
        }
    };

    load_e(e0);

    for (int ei = 0; ei < EPB; ++ei) {
        const int e = e0 + ei;
        __syncthreads();   // previous iteration's gathers done before overwrite
        // convert prefetched f32 -> duplicated half2 pairs, write 16B/thread/slot
#pragma unroll
        for (int j = 0; j < SIT; ++j) {
            int idx = tid + j * TPB;
            int a   = idx / (S_N / 4);
            int s4  = idx - a * (S_N / 4);
            float4 v = pf[j];
            float  x = pe[j];
            union { half2_t h[4]; float4 f; } u;
            u.h[0] = __builtin_amdgcn_cvt_pkrtz(v.x, v.y);
            u.h[1] = __builtin_amdgcn_cvt_pkrtz(v.y, v.z);
            u.h[2] = __builtin_amdgcn_cvt_pkrtz(v.z, v.w);
            u.h[3] = __builtin_amdgcn_cvt_pkrtz(v.w, x);
            *(float4*)&lds_rf[a * S_N + s4 * 4] = u.f;
        }
        __syncthreads();

        // issue next element's rf loads; latency hides under compute below
        if (ei + 1 < EPB) load_e(e + 1);

        const float* __restrict__ drx_row = d_rx + (size_t)e * NPIX_N;
        const float* __restrict__ ap_row  = apod + (size_t)e * NPIX_N;

        float drx[PXT], ap[PXT];
#pragma unroll
        for (int k = 0; k < PXT; ++k) {     // batched stream loads
            drx[k] = drx_row[px0 + k * TPB];
            ap[k]  = ap_row[px0 + k * TPB];
        }

#pragma unroll
        for (int k = 0; k < PXT; ++k) {
#pragma unroll
            for (int a = 0; a < A_N; ++a) {
                float delay = dta[a][k] + drx[k];
                float x0 = floorf(delay);
                float w  = delay - x0;
                int i0 = (int)x0;
                i0 = min(max(i0, 0), S_N - 2);   // no-op for this data; safety
                half2_t hv = lds_rf[a * S_N + i0];   // one ds_read_b32: {v0,v1}
                float v0 = (float)hv[0];
                float v1 = (float)hv[1];
                acc[a][k] += (v0 + w * (v1 - v0)) * ap[k];
            }
        }
    }

#pragma unroll
    for (int a = 0; a < A_N; ++a)
#pragma unroll
        for (int k = 0; k < PXT; ++k)
            atomicAdd(&out[a * NPIX_N + px0 + k * TPB], acc[a][k]);
}

extern "C" void kernel_launch(void* const* d_in, const int* in_sizes, int n_in,
                              void* d_out, int out_size, void* d_ws, size_t ws_size,
                              hipStream_t stream) {
    const float* d_tx = (const float*)d_in[0];
    const float* d_rx = (const float*)d_in[1];
    const float* apod = (const float*)d_in[2];
    const float* rf   = (const float*)d_in[3];
    const float* t0   = (const float*)d_in[4];
    float* out = (float*)d_out;

    hipMemsetAsync(out, 0, (size_t)out_size * sizeof(float), stream);
    dim3 grid(TILES, ESPLIT);
    das_kernel<<<grid, TPB, 0, stream>>>(d_tx, d_rx, apod, rf, t0, out);
}